// Round 15
// baseline (1734.743 us; speedup 1.0000x reference)
//
#include <hip/hip_runtime.h>
#include <hip/hip_bf16.h>

// CGCNN forward, MI355X. R14: R13 + (a) nontemporal ef loads in edge_a (keep
// the 12.8MB x16 gather table L2-resident; ef stream has no reuse), (b) 2x
// unrolled nodered edge loop (2 half8 loads in flight), (c) float4 prep_efg.
//   prep: CSR build (deg/scan/scatter), ef16 gathered into CSR order (48-pad)
//   3x: pass A (CSR order): z = [x[i1]|x[i2]|ef] @ Wf[l] (f16 MFMA, fp32 acc;
//         bf cancels in train-mode BN) + column sum/sumsq + store z pairs
//       pass B: wave-per-node: stream contiguous zp run (half8) -> BN ->
//         sig*softplus -> register reduce -> one float4 store per node+stats
//       node apply: BN2 -> softplus -> new x (last layer also crystal atomics)
//   crystal seg-mean -> softplus(@Wc+bc) -> @Wo+bo

#define NN 100000
#define NE 1600000
#define NC 2000
#define KPAD 176
#define EFW 48
#define EPSB 1e-5f
#define NCH 1000
#define CH 100

typedef _Float16 f16;
typedef _Float16 half8 __attribute__((ext_vector_type(8)));
typedef _Float16 half4 __attribute__((ext_vector_type(4)));
typedef _Float16 half2v __attribute__((ext_vector_type(2)));
typedef float f32x16 __attribute__((ext_vector_type(16)));

__device__ __forceinline__ f32x16 zero16() {
    f32x16 v;
#pragma unroll
    for (int i = 0; i < 16; i++) v[i] = 0.f;
    return v;
}
__device__ __forceinline__ float fsoftplus(float x) {
    return fmaxf(x, 0.f) + __logf(1.f + __expf(-fabsf(x)));
}
__device__ __forceinline__ float fsigmoid(float x) {
    return __fdividef(1.f, 1.f + __expf(-x));
}

// ---------- prep ----------
__global__ void k_prep_x(const int* __restrict__ nf, const float* __restrict__ emb,
                         float* __restrict__ xf, f16* __restrict__ x16) {
    for (int idx = blockIdx.x * blockDim.x + threadIdx.x; idx < NN * 64;
         idx += gridDim.x * blockDim.x) {
        int n = idx >> 6, k = idx & 63;
        float v = emb[nf[n] * 64 + k];
        xf[idx] = v;
        x16[idx] = (f16)v;
    }
}

__global__ void k_deg(const int* __restrict__ idx1, const int* __restrict__ idx3,
                      int* deg1, float* cnt3) {
    for (int i = blockIdx.x * blockDim.x + threadIdx.x; i < NE;
         i += gridDim.x * blockDim.x) {
        atomicAdd(&deg1[idx1[i]], 1);
        if (i < NN) atomicAdd(&cnt3[idx3[i]], 1.f);
    }
}

// exclusive prefix sum of deg -> rp (NCH chunks of CH)
__global__ void k_scan_a(const int* __restrict__ deg, int* __restrict__ csum) {
    int t = blockIdx.x * blockDim.x + threadIdx.x;
    if (t < NCH) {
        int s = 0;
        int base = t * CH;
        for (int i = 0; i < CH; i++) s += deg[base + i];
        csum[t] = s;
    }
}
__global__ void k_scan_b(const int* __restrict__ csum, int* __restrict__ coff) {
    __shared__ int sc[256];
    int t = threadIdx.x;
    int v[4];
    int part = 0;
#pragma unroll
    for (int q = 0; q < 4; q++) {
        int idx = 4 * t + q;
        v[q] = (idx < NCH) ? csum[idx] : 0;
        part += v[q];
    }
    sc[t] = part;
    __syncthreads();
    for (int off = 1; off < 256; off <<= 1) {
        int add = (t >= off) ? sc[t - off] : 0;
        __syncthreads();
        sc[t] += add;
        __syncthreads();
    }
    int run = sc[t] - part;  // exclusive
#pragma unroll
    for (int q = 0; q < 4; q++) {
        int idx = 4 * t + q;
        if (idx < NCH) coff[idx] = run;
        run += v[q];
    }
}
__global__ void k_scan_c(const int* __restrict__ deg, const int* __restrict__ coff,
                         int* __restrict__ rp) {
    int t = blockIdx.x * blockDim.x + threadIdx.x;
    if (t < NCH) {
        int running = coff[t];
        int base = t * CH;
        for (int i = 0; i < CH; i++) {
            rp[base + i] = running;
            running += deg[base + i];
        }
    }
}

__global__ void k_scatter(const int* __restrict__ idx1, const int* __restrict__ idx2,
                          const int* __restrict__ rp1, int* cur1, int* elist1,
                          int* i1r, int* i2r) {
    for (int e = blockIdx.x * blockDim.x + threadIdx.x; e < NE;
         e += gridDim.x * blockDim.x) {
        int n1 = idx1[e];
        int p = rp1[n1] + atomicAdd(&cur1[n1], 1);
        elist1[p] = e;
        i1r[p] = n1;
        i2r[p] = idx2[e];
    }
}

// ef16p[p][0:48] = pad48(edge_fea[elist1[p]])  (CSR-permuted, f16)
// 12 threads/row, float4 (unaligned-ok) loads, half4 stores.
__global__ void k_prep_efg(const float* __restrict__ ef, const int* __restrict__ elist1,
                           f16* __restrict__ ef16p) {
    for (long idx = (long)blockIdx.x * blockDim.x + threadIdx.x; idx < (long)NE * 12;
         idx += (long)gridDim.x * blockDim.x) {
        long p = idx / 12;
        int t = (int)(idx - p * 12);
        int e = elist1[p];
        int k0 = t * 4;
        half4 h;
        if (k0 + 3 < 41) {
            float4 v = *reinterpret_cast<const float4*>(ef + (size_t)e * 41 + k0);
            h[0] = (f16)v.x; h[1] = (f16)v.y; h[2] = (f16)v.z; h[3] = (f16)v.w;
        } else {
#pragma unroll
            for (int u = 0; u < 4; u++) {
                int k = k0 + u;
                h[u] = (f16)((k < 41) ? ef[(size_t)e * 41 + k] : 0.f);
            }
        }
        *reinterpret_cast<half4*>(ef16p + p * EFW + k0) = h;
    }
}

// WT[col][k] = Wf_l[k][col] (f16, k padded 169->176)
__global__ void k_wt(const float* __restrict__ Wf_l, f16* __restrict__ WT) {
    for (int idx = blockIdx.x * blockDim.x + threadIdx.x; idx < 128 * KPAD;
         idx += gridDim.x * blockDim.x) {
        int col = idx / KPAD, k = idx % KPAD;
        float v = (k < 169) ? Wf_l[k * 128 + col] : 0.f;
        WT[idx] = (f16)v;
    }
}

// ---------- pass A: CSR-ordered GEMM + stats + z store (R3 variant) ----------
// Block = 4 waves over a 64-edge tile: wave (h,ch) = 32-edge subtile h,
// col-half ch. B-fragments in REGISTERS (empirically fastest across 8
// variants; B-in-LDS costs ~50us of ds_read latency at equal occupancy).
__global__ __launch_bounds__(256) void k_edge_a(
    const f16* __restrict__ x16, const f16* __restrict__ ef16p,
    const f16* __restrict__ WT, const int* __restrict__ i1r,
    const int* __restrict__ i2r, float* __restrict__ estats,
    half2v* __restrict__ zp) {
    __shared__ float lst[256];
    int tid = threadIdx.x;
    int lane = tid & 63;
    int w = tid >> 6;
    int h = w >> 1, ch = w & 1;
    int c = lane & 31, kg = lane >> 5;

    half8 bfr[2][11];
#pragma unroll
    for (int t = 0; t < 2; t++) {
        int col = 32 * ch + 64 * t + c;
        const f16* bp = WT + col * KPAD + kg * 8;
#pragma unroll
        for (int s = 0; s < 11; s++)
            bfr[t][s] = *reinterpret_cast<const half8*>(bp + s * 16);
    }

    lst[tid] = 0.f;
    __syncthreads();

    float s1[2] = {0.f, 0.f}, s2[2] = {0.f, 0.f};
    const int NT = NE / 64;
    for (int tile = blockIdx.x; tile < NT; tile += gridDim.x) {
        int p0 = tile * 64 + h * 32;
        long p = p0 + c;
        int i1 = i1r[p], i2 = i2r[p];
        f32x16 acc0 = zero16(), acc1 = zero16();
#pragma unroll
        for (int s = 0; s < 4; s++) {
            half8 a = *reinterpret_cast<const half8*>(x16 + (size_t)i1 * 64 + s * 16 + kg * 8);
            acc0 = __builtin_amdgcn_mfma_f32_32x32x16_f16(a, bfr[0][s], acc0, 0, 0, 0);
            acc1 = __builtin_amdgcn_mfma_f32_32x32x16_f16(a, bfr[1][s], acc1, 0, 0, 0);
        }
#pragma unroll
        for (int s = 0; s < 4; s++) {
            half8 a = *reinterpret_cast<const half8*>(x16 + (size_t)i2 * 64 + s * 16 + kg * 8);
            acc0 = __builtin_amdgcn_mfma_f32_32x32x16_f16(a, bfr[0][4 + s], acc0, 0, 0, 0);
            acc1 = __builtin_amdgcn_mfma_f32_32x32x16_f16(a, bfr[1][4 + s], acc1, 0, 0, 0);
        }
#pragma unroll
        for (int s = 0; s < 3; s++) {
            // nt load: ef stream has zero reuse -- keep it from evicting the
            // x16 gather table (the latency bottleneck) out of L2.
            half8 a = __builtin_nontemporal_load(
                reinterpret_cast<const half8*>(ef16p + p * EFW + s * 16 + kg * 8));
            acc0 = __builtin_amdgcn_mfma_f32_32x32x16_f16(a, bfr[0][8 + s], acc0, 0, 0, 0);
            acc1 = __builtin_amdgcn_mfma_f32_32x32x16_f16(a, bfr[1][8 + s], acc1, 0, 0, 0);
        }
#pragma unroll
        for (int r = 0; r < 16; r++) {
            float v0 = acc0[r], v1 = acc1[r];
            s1[0] += v0; s2[0] += v0 * v0;
            s1[1] += v1; s2[1] += v1 * v1;
            int row = (r & 3) + 8 * (r >> 2) + 4 * kg;
            half2v pr;
            pr[0] = (f16)v0;  // gate col j = 32*ch+c
            pr[1] = (f16)v1;  // conv col 64+j
            __builtin_nontemporal_store(pr, &zp[(size_t)(p0 + row) * 64 + 32 * ch + c]);
        }
    }
#pragma unroll
    for (int t = 0; t < 2; t++) {
        s1[t] += __shfl_xor(s1[t], 32, 64);
        s2[t] += __shfl_xor(s2[t], 32, 64);
    }
    if (kg == 0) {
#pragma unroll
        for (int t = 0; t < 2; t++) {
            int col = 32 * ch + 64 * t + c;
            atomicAdd(&lst[col], s1[t]);
            atomicAdd(&lst[128 + col], s2[t]);
        }
    }
    __syncthreads();
    atomicAdd(&estats[tid], lst[tid]);
}

// ---------- pass B: wave-per-node reduce, half8/lane, 2x unrolled ----------
// Lane l: c4 = l&15 owns cols 4c4..4c4+3; sub = l>>4 takes edges q = sub,
// sub+4, ... 2x unroll keeps two independent 16B loads in flight.
__global__ __launch_bounds__(256) void k_nodered(
    const f16* __restrict__ zph, const int* __restrict__ rp1,
    const int* __restrict__ deg1, const float* __restrict__ estats,
    const float* __restrict__ g1, const float* __restrict__ be1,
    float* __restrict__ raw_out, float* __restrict__ nstats) {
    __shared__ float sstat[128];
    int tid = threadIdx.x;
    int lane = tid & 63;
    int c4 = lane & 15, sub = lane >> 4;
    int wv = tid >> 6;
    if (tid < 128) sstat[tid] = 0.f;
    __syncthreads();
    float ag[4], bg[4], ac[4], bc[4];
#pragma unroll
    for (int u = 0; u < 4; u++) {
        int j = 4 * c4 + u;
        float mg = estats[j] * (1.f / NE);
        float vg = estats[128 + j] * (1.f / NE) - mg * mg;
        ag[u] = g1[j] * rsqrtf(vg + EPSB);
        bg[u] = be1[j] - mg * ag[u];
        float mc = estats[64 + j] * (1.f / NE);
        float vc = estats[192 + j] * (1.f / NE) - mc * mc;
        ac[u] = g1[64 + j] * rsqrtf(vc + EPSB);
        bc[u] = be1[64 + j] - mc * ac[u];
    }
    float p1[4] = {0.f, 0.f, 0.f, 0.f}, p2[4] = {0.f, 0.f, 0.f, 0.f};
    for (int n = blockIdx.x * 4 + wv; n < NN; n += gridDim.x * 4) {
        int st = rp1[n], d = deg1[n];
        float a[4] = {0.f, 0.f, 0.f, 0.f};
        int q = sub;
        for (; q + 4 < d; q += 8) {
            half8 z0 = __builtin_nontemporal_load(
                reinterpret_cast<const half8*>(zph + (size_t)(st + q) * 128 + 8 * c4));
            half8 z1 = __builtin_nontemporal_load(
                reinterpret_cast<const half8*>(zph + (size_t)(st + q + 4) * 128 + 8 * c4));
#pragma unroll
            for (int u = 0; u < 4; u++) {
                a[u] += fsigmoid((float)z0[2 * u] * ag[u] + bg[u]) *
                        fsoftplus((float)z0[2 * u + 1] * ac[u] + bc[u]);
                a[u] += fsigmoid((float)z1[2 * u] * ag[u] + bg[u]) *
                        fsoftplus((float)z1[2 * u + 1] * ac[u] + bc[u]);
            }
        }
        if (q < d) {
            half8 z0 = __builtin_nontemporal_load(
                reinterpret_cast<const half8*>(zph + (size_t)(st + q) * 128 + 8 * c4));
#pragma unroll
            for (int u = 0; u < 4; u++) {
                a[u] += fsigmoid((float)z0[2 * u] * ag[u] + bg[u]) *
                        fsoftplus((float)z0[2 * u + 1] * ac[u] + bc[u]);
            }
        }
#pragma unroll
        for (int u = 0; u < 4; u++) {
            a[u] += __shfl_xor(a[u], 16, 64);
            a[u] += __shfl_xor(a[u], 32, 64);
        }
        if (sub == 0) {
            float dn = fmaxf((float)d, 1.f);
            float rr[4];
#pragma unroll
            for (int u = 0; u < 4; u++) {
                rr[u] = __fdividef(a[u], dn);
                p1[u] += rr[u];
                p2[u] += rr[u] * rr[u];
            }
            float4 r4;
            r4.x = rr[0]; r4.y = rr[1]; r4.z = rr[2]; r4.w = rr[3];
            *reinterpret_cast<float4*>(raw_out + (size_t)n * 64 + 4 * c4) = r4;
        }
    }
    if (sub == 0) {
#pragma unroll
        for (int u = 0; u < 4; u++) {
            atomicAdd(&sstat[4 * c4 + u], p1[u]);
            atomicAdd(&sstat[64 + 4 * c4 + u], p2[u]);
        }
    }
    __syncthreads();
    if (tid < 128) atomicAdd(&nstats[tid], sstat[tid]);
}

// ---------- node apply: BN2 + softplus (+ crystal pool on last layer) ----------
template <bool LAST>
__global__ __launch_bounds__(256) void k_node_apply(
    const float* __restrict__ raw_in, const float* __restrict__ nstats,
    const float* __restrict__ g2, const float* __restrict__ be2,
    float* __restrict__ xf, f16* __restrict__ x16, const int* __restrict__ idx3,
    float* __restrict__ crsum) {
    for (int idx = blockIdx.x * blockDim.x + threadIdx.x; idx < NN * 64;
         idx += gridDim.x * blockDim.x) {
        int n = idx >> 6, j = idx & 63;
        float m = nstats[j] * (1.f / NN);
        float var = nstats[64 + j] * (1.f / NN) - m * m;
        float rs = rsqrtf(var + EPSB);
        float a = g2[j] * rs;
        float b = be2[j] - m * a;
        float v = fsoftplus(xf[idx] + raw_in[idx] * a + b);
        if (LAST) {
            atomicAdd(&crsum[(size_t)idx3[n] * 64 + j], v);
        } else {
            xf[idx] = v;
            x16[idx] = (f16)v;
        }
    }
}

// ---------- output MLP ----------
__global__ __launch_bounds__(128) void k_out(const float* __restrict__ crsum,
                                             const float* __restrict__ cnt3,
                                             const float* __restrict__ Wc,
                                             const float* __restrict__ bcv,
                                             const float* __restrict__ Wo,
                                             const float* __restrict__ bo,
                                             float* __restrict__ out) {
    __shared__ float crym[64];
    __shared__ float red[4];
    int c = blockIdx.x, tid = threadIdx.x;
    if (tid < 64) crym[tid] = crsum[c * 64 + tid] / fmaxf(cnt3[c], 1.f);
    __syncthreads();
    float hv = bcv[tid];
#pragma unroll
    for (int k = 0; k < 64; k++) hv += crym[k] * Wc[k * 128 + tid];
    hv = fsoftplus(hv);
    float o0 = hv * Wo[tid * 2 + 0];
    float o1 = hv * Wo[tid * 2 + 1];
#pragma unroll
    for (int off = 32; off > 0; off >>= 1) {
        o0 += __shfl_down(o0, off, 64);
        o1 += __shfl_down(o1, off, 64);
    }
    int wv = tid >> 6;
    if ((tid & 63) == 0) { red[wv * 2] = o0; red[wv * 2 + 1] = o1; }
    __syncthreads();
    if (tid == 0) {
        out[c * 2 + 0] = red[0] + red[2] + bo[0];
        out[c * 2 + 1] = red[1] + red[3] + bo[1];
    }
}

// ---------- launch ----------
static inline size_t al256(size_t x) { return (x + 255) & ~(size_t)255; }

extern "C" void kernel_launch(void* const* d_in, const int* in_sizes, int n_in,
                              void* d_out, int out_size, void* d_ws, size_t ws_size,
                              hipStream_t stream) {
    const int* node_fea = (const int*)d_in[0];
    const float* edge_fea = (const float*)d_in[1];
    const int* idx1 = (const int*)d_in[2];
    const int* idx2 = (const int*)d_in[3];
    const int* idx3 = (const int*)d_in[4];
    const float* emb = (const float*)d_in[5];
    const float* Wf = (const float*)d_in[6];
    // d_in[7] = bf: cancels inside training-mode BN, unused.
    const float* g1 = (const float*)d_in[8];
    const float* be1 = (const float*)d_in[9];
    const float* g2 = (const float*)d_in[10];
    const float* be2 = (const float*)d_in[11];
    const float* Wc = (const float*)d_in[12];
    const float* bc = (const float*)d_in[13];
    const float* Wo = (const float*)d_in[14];
    const float* bo = (const float*)d_in[15];
    float* out = (float*)d_out;
    unsigned char* ws = (unsigned char*)d_ws;

    size_t off = 0;
    size_t o_xf = off;     off = al256(off + (size_t)NN * 64 * 4);
    size_t o_x16 = off;    off = al256(off + (size_t)NN * 64 * 2);
    size_t o_efp = off;    off = al256(off + (size_t)NE * EFW * 2);
    size_t o_WT = off;     off = al256(off + (size_t)128 * KPAD * 2);
    size_t o_rp1 = off;    off = al256(off + (size_t)NN * 4);
    size_t o_el1 = off;    off = al256(off + (size_t)NE * 4);
    size_t o_i1r = off;    off = al256(off + (size_t)NE * 4);
    size_t o_i2r = off;    off = al256(off + (size_t)NE * 4);
    size_t o_raw = off;    off = al256(off + (size_t)NN * 64 * 4);
    // prep-zero region (one memset):
    size_t o_deg1 = off;   off = al256(off + (size_t)NN * 4);
    size_t o_cur1 = off;   off = al256(off + (size_t)NN * 4);
    size_t o_cnt3 = off;   off = al256(off + (size_t)NC * 4);
    size_t o_csum = off;   off = al256(off + 1024 * 4);
    size_t o_coff = off;   off = al256(off + 1024 * 4);
    size_t o_crsum = off;  off = al256(off + (size_t)NC * 64 * 4);
    size_t prep_zero_end = off;
    // per-layer-zero region (tiny memset per layer):
    size_t o_estats = off; off = al256(off + 256 * 4);
    size_t o_nstats = off; off = al256(off + 128 * 4);
    size_t layer_zero_end = off;
    size_t o_z = off;      off = al256(off + (size_t)NE * 64 * 4);
    (void)ws_size;

    float* xf = (float*)(ws + o_xf);
    f16* x16 = (f16*)(ws + o_x16);
    f16* ef16p = (f16*)(ws + o_efp);
    f16* WT = (f16*)(ws + o_WT);
    int* rp1 = (int*)(ws + o_rp1);
    int* elist1 = (int*)(ws + o_el1);
    int* i1r = (int*)(ws + o_i1r);
    int* i2r = (int*)(ws + o_i2r);
    float* raw = (float*)(ws + o_raw);
    int* deg1 = (int*)(ws + o_deg1);
    int* cur1 = (int*)(ws + o_cur1);
    float* cnt3 = (float*)(ws + o_cnt3);
    int* csum = (int*)(ws + o_csum);
    int* coff = (int*)(ws + o_coff);
    float* crsum = (float*)(ws + o_crsum);
    float* estats = (float*)(ws + o_estats);
    float* nstats = (float*)(ws + o_nstats);
    f16* zph = (f16*)(ws + o_z);
    half2v* zp = (half2v*)(ws + o_z);

    hipMemsetAsync(ws + o_deg1, 0, prep_zero_end - o_deg1, stream);
    k_prep_x<<<1024, 256, 0, stream>>>(node_fea, emb, xf, x16);
    k_deg<<<2048, 256, 0, stream>>>(idx1, idx3, deg1, cnt3);
    k_scan_a<<<4, 256, 0, stream>>>(deg1, csum);
    k_scan_b<<<1, 256, 0, stream>>>(csum, coff);
    k_scan_c<<<4, 256, 0, stream>>>(deg1, coff, rp1);
    k_scatter<<<2048, 256, 0, stream>>>(idx1, idx2, rp1, cur1, elist1, i1r, i2r);
    k_prep_efg<<<8192, 256, 0, stream>>>(edge_fea, elist1, ef16p);

    for (int l = 0; l < 3; l++) {
        const float* Wf_l = Wf + (size_t)l * 169 * 128;
        hipMemsetAsync(ws + o_estats, 0, layer_zero_end - o_estats, stream);
        k_wt<<<88, 256, 0, stream>>>(Wf_l, WT);
        k_edge_a<<<2048, 256, 0, stream>>>(x16, ef16p, WT, i1r, i2r, estats, zp);
        k_nodered<<<4096, 256, 0, stream>>>(zph, rp1, deg1, estats, g1 + l * 128,
                                            be1 + l * 128, raw, nstats);
        if (l < 2) {
            k_node_apply<false><<<1024, 256, 0, stream>>>(raw, nstats, g2 + l * 64,
                                                          be2 + l * 64, xf, x16,
                                                          idx3, crsum);
        } else {
            k_node_apply<true><<<1024, 256, 0, stream>>>(raw, nstats, g2 + l * 64,
                                                         be2 + l * 64, xf, x16,
                                                         idx3, crsum);
        }
    }
    k_out<<<2000, 128, 0, stream>>>(crsum, cnt3, Wc, bc, Wo, bo, out);
}

// Round 16
// 1589.483 us; speedup vs baseline: 1.0914x; 1.0914x over previous
//
#include <hip/hip_runtime.h>
#include <hip/hip_bf16.h>

// CGCNN forward, MI355X. R15 = exact revert to R13 (best: 1596us).
// R14's nontemporal ef loads refetched shared cache lines (+53MB FETCH,
// +32us/dispatch) — nt loads are only safe when one instruction consumes
// the full line. Keep: nt z-store (paired 4B layout, full sectors),
// half8 nodered, R3 edge_a (B in registers).
//   prep: CSR build (deg/scan/scatter), ef16 gathered into CSR order (48-pad)
//   3x: pass A (CSR order): z = [x[i1]|x[i2]|ef] @ Wf[l] (f16 MFMA, fp32 acc;
//         bf cancels in train-mode BN) + column sum/sumsq + store z pairs
//       pass B: wave-per-node: stream contiguous zp run (half8) -> BN ->
//         sig*softplus -> register reduce -> one float4 store per node+stats
//       node apply: BN2 -> softplus -> new x (last layer also crystal atomics)
//   crystal seg-mean -> softplus(@Wc+bc) -> @Wo+bo

#define NN 100000
#define NE 1600000
#define NC 2000
#define KPAD 176
#define EFW 48
#define EPSB 1e-5f
#define NCH 1000
#define CH 100

typedef _Float16 f16;
typedef _Float16 half8 __attribute__((ext_vector_type(8)));
typedef _Float16 half2v __attribute__((ext_vector_type(2)));
typedef float f32x16 __attribute__((ext_vector_type(16)));

__device__ __forceinline__ f32x16 zero16() {
    f32x16 v;
#pragma unroll
    for (int i = 0; i < 16; i++) v[i] = 0.f;
    return v;
}
__device__ __forceinline__ float fsoftplus(float x) {
    return fmaxf(x, 0.f) + __logf(1.f + __expf(-fabsf(x)));
}
__device__ __forceinline__ float fsigmoid(float x) {
    return __fdividef(1.f, 1.f + __expf(-x));
}

// ---------- prep ----------
__global__ void k_prep_x(const int* __restrict__ nf, const float* __restrict__ emb,
                         float* __restrict__ xf, f16* __restrict__ x16) {
    for (int idx = blockIdx.x * blockDim.x + threadIdx.x; idx < NN * 64;
         idx += gridDim.x * blockDim.x) {
        int n = idx >> 6, k = idx & 63;
        float v = emb[nf[n] * 64 + k];
        xf[idx] = v;
        x16[idx] = (f16)v;
    }
}

__global__ void k_deg(const int* __restrict__ idx1, const int* __restrict__ idx3,
                      int* deg1, float* cnt3) {
    for (int i = blockIdx.x * blockDim.x + threadIdx.x; i < NE;
         i += gridDim.x * blockDim.x) {
        atomicAdd(&deg1[idx1[i]], 1);
        if (i < NN) atomicAdd(&cnt3[idx3[i]], 1.f);
    }
}

// exclusive prefix sum of deg -> rp (NCH chunks of CH)
__global__ void k_scan_a(const int* __restrict__ deg, int* __restrict__ csum) {
    int t = blockIdx.x * blockDim.x + threadIdx.x;
    if (t < NCH) {
        int s = 0;
        int base = t * CH;
        for (int i = 0; i < CH; i++) s += deg[base + i];
        csum[t] = s;
    }
}
__global__ void k_scan_b(const int* __restrict__ csum, int* __restrict__ coff) {
    __shared__ int sc[256];
    int t = threadIdx.x;
    int v[4];
    int part = 0;
#pragma unroll
    for (int q = 0; q < 4; q++) {
        int idx = 4 * t + q;
        v[q] = (idx < NCH) ? csum[idx] : 0;
        part += v[q];
    }
    sc[t] = part;
    __syncthreads();
    for (int off = 1; off < 256; off <<= 1) {
        int add = (t >= off) ? sc[t - off] : 0;
        __syncthreads();
        sc[t] += add;
        __syncthreads();
    }
    int run = sc[t] - part;  // exclusive
#pragma unroll
    for (int q = 0; q < 4; q++) {
        int idx = 4 * t + q;
        if (idx < NCH) coff[idx] = run;
        run += v[q];
    }
}
__global__ void k_scan_c(const int* __restrict__ deg, const int* __restrict__ coff,
                         int* __restrict__ rp) {
    int t = blockIdx.x * blockDim.x + threadIdx.x;
    if (t < NCH) {
        int running = coff[t];
        int base = t * CH;
        for (int i = 0; i < CH; i++) {
            rp[base + i] = running;
            running += deg[base + i];
        }
    }
}

__global__ void k_scatter(const int* __restrict__ idx1, const int* __restrict__ idx2,
                          const int* __restrict__ rp1, int* cur1, int* elist1,
                          int* i1r, int* i2r) {
    for (int e = blockIdx.x * blockDim.x + threadIdx.x; e < NE;
         e += gridDim.x * blockDim.x) {
        int n1 = idx1[e];
        int p = rp1[n1] + atomicAdd(&cur1[n1], 1);
        elist1[p] = e;
        i1r[p] = n1;
        i2r[p] = idx2[e];
    }
}

// ef16p[p][0:48] = pad48(edge_fea[elist1[p]])  (CSR-permuted, f16)
__global__ void k_prep_efg(const float* __restrict__ ef, const int* __restrict__ elist1,
                           f16* __restrict__ ef16p) {
    for (long idx = (long)blockIdx.x * blockDim.x + threadIdx.x; idx < (long)NE * EFW;
         idx += (long)gridDim.x * blockDim.x) {
        long p = idx / EFW;
        int k = (int)(idx - p * EFW);
        int e = elist1[p];
        float v = (k < 41) ? ef[(size_t)e * 41 + k] : 0.f;
        ef16p[idx] = (f16)v;
    }
}

// WT[col][k] = Wf_l[k][col] (f16, k padded 169->176)
__global__ void k_wt(const float* __restrict__ Wf_l, f16* __restrict__ WT) {
    for (int idx = blockIdx.x * blockDim.x + threadIdx.x; idx < 128 * KPAD;
         idx += gridDim.x * blockDim.x) {
        int col = idx / KPAD, k = idx % KPAD;
        float v = (k < 169) ? Wf_l[k * 128 + col] : 0.f;
        WT[idx] = (f16)v;
    }
}

// ---------- pass A: CSR-ordered GEMM + stats + z store (R3 variant) ----------
// Block = 4 waves over a 64-edge tile: wave (h,ch) = 32-edge subtile h,
// col-half ch. B-fragments in REGISTERS (empirically fastest across 8
// variants; B-in-LDS costs ~50us of ds_read latency at equal occupancy).
__global__ __launch_bounds__(256) void k_edge_a(
    const f16* __restrict__ x16, const f16* __restrict__ ef16p,
    const f16* __restrict__ WT, const int* __restrict__ i1r,
    const int* __restrict__ i2r, float* __restrict__ estats,
    half2v* __restrict__ zp) {
    __shared__ float lst[256];
    int tid = threadIdx.x;
    int lane = tid & 63;
    int w = tid >> 6;
    int h = w >> 1, ch = w & 1;
    int c = lane & 31, kg = lane >> 5;

    half8 bfr[2][11];
#pragma unroll
    for (int t = 0; t < 2; t++) {
        int col = 32 * ch + 64 * t + c;
        const f16* bp = WT + col * KPAD + kg * 8;
#pragma unroll
        for (int s = 0; s < 11; s++)
            bfr[t][s] = *reinterpret_cast<const half8*>(bp + s * 16);
    }

    lst[tid] = 0.f;
    __syncthreads();

    float s1[2] = {0.f, 0.f}, s2[2] = {0.f, 0.f};
    const int NT = NE / 64;
    for (int tile = blockIdx.x; tile < NT; tile += gridDim.x) {
        int p0 = tile * 64 + h * 32;
        long p = p0 + c;
        int i1 = i1r[p], i2 = i2r[p];
        f32x16 acc0 = zero16(), acc1 = zero16();
#pragma unroll
        for (int s = 0; s < 4; s++) {
            half8 a = *reinterpret_cast<const half8*>(x16 + (size_t)i1 * 64 + s * 16 + kg * 8);
            acc0 = __builtin_amdgcn_mfma_f32_32x32x16_f16(a, bfr[0][s], acc0, 0, 0, 0);
            acc1 = __builtin_amdgcn_mfma_f32_32x32x16_f16(a, bfr[1][s], acc1, 0, 0, 0);
        }
#pragma unroll
        for (int s = 0; s < 4; s++) {
            half8 a = *reinterpret_cast<const half8*>(x16 + (size_t)i2 * 64 + s * 16 + kg * 8);
            acc0 = __builtin_amdgcn_mfma_f32_32x32x16_f16(a, bfr[0][4 + s], acc0, 0, 0, 0);
            acc1 = __builtin_amdgcn_mfma_f32_32x32x16_f16(a, bfr[1][4 + s], acc1, 0, 0, 0);
        }
#pragma unroll
        for (int s = 0; s < 3; s++) {
            half8 a = *reinterpret_cast<const half8*>(ef16p + p * EFW + s * 16 + kg * 8);
            acc0 = __builtin_amdgcn_mfma_f32_32x32x16_f16(a, bfr[0][8 + s], acc0, 0, 0, 0);
            acc1 = __builtin_amdgcn_mfma_f32_32x32x16_f16(a, bfr[1][8 + s], acc1, 0, 0, 0);
        }
#pragma unroll
        for (int r = 0; r < 16; r++) {
            float v0 = acc0[r], v1 = acc1[r];
            s1[0] += v0; s2[0] += v0 * v0;
            s1[1] += v1; s2[1] += v1 * v1;
            int row = (r & 3) + 8 * (r >> 2) + 4 * kg;
            half2v pr;
            pr[0] = (f16)v0;  // gate col j = 32*ch+c
            pr[1] = (f16)v1;  // conv col 64+j
            // nt store: 32 lanes x 4B contiguous = full sectors; bypass L2 so
            // the 400MB z stream doesn't evict the x16 gather table.
            __builtin_nontemporal_store(pr, &zp[(size_t)(p0 + row) * 64 + 32 * ch + c]);
        }
    }
#pragma unroll
    for (int t = 0; t < 2; t++) {
        s1[t] += __shfl_xor(s1[t], 32, 64);
        s2[t] += __shfl_xor(s2[t], 32, 64);
    }
    if (kg == 0) {
#pragma unroll
        for (int t = 0; t < 2; t++) {
            int col = 32 * ch + 64 * t + c;
            atomicAdd(&lst[col], s1[t]);
            atomicAdd(&lst[128 + col], s2[t]);
        }
    }
    __syncthreads();
    atomicAdd(&estats[tid], lst[tid]);
}

// ---------- pass B: wave-per-node reduce, 4 edges/iter, half8/lane ----------
// Lane l: c4 = l&15 owns cols 4c4..4c4+3 (pairs = 8 consecutive f16 at
// byte offset 16*c4); sub = l>>4 takes edges q = sub, sub+4, ... A wave
// covers 4 full 256B edge rows per iteration. Reduce via shfl_xor(16,32).
__global__ __launch_bounds__(256) void k_nodered(
    const f16* __restrict__ zph, const int* __restrict__ rp1,
    const int* __restrict__ deg1, const float* __restrict__ estats,
    const float* __restrict__ g1, const float* __restrict__ be1,
    float* __restrict__ raw_out, float* __restrict__ nstats) {
    __shared__ float sstat[128];
    int tid = threadIdx.x;
    int lane = tid & 63;
    int c4 = lane & 15, sub = lane >> 4;
    int wv = tid >> 6;
    if (tid < 128) sstat[tid] = 0.f;
    __syncthreads();
    float ag[4], bg[4], ac[4], bc[4];
#pragma unroll
    for (int u = 0; u < 4; u++) {
        int j = 4 * c4 + u;
        float mg = estats[j] * (1.f / NE);
        float vg = estats[128 + j] * (1.f / NE) - mg * mg;
        ag[u] = g1[j] * rsqrtf(vg + EPSB);
        bg[u] = be1[j] - mg * ag[u];
        float mc = estats[64 + j] * (1.f / NE);
        float vc = estats[192 + j] * (1.f / NE) - mc * mc;
        ac[u] = g1[64 + j] * rsqrtf(vc + EPSB);
        bc[u] = be1[64 + j] - mc * ac[u];
    }
    float p1[4] = {0.f, 0.f, 0.f, 0.f}, p2[4] = {0.f, 0.f, 0.f, 0.f};
    for (int n = blockIdx.x * 4 + wv; n < NN; n += gridDim.x * 4) {
        int st = rp1[n], d = deg1[n];
        float a[4] = {0.f, 0.f, 0.f, 0.f};
        for (int q = sub; q < d; q += 4) {
            half8 z = __builtin_nontemporal_load(
                reinterpret_cast<const half8*>(zph + (size_t)(st + q) * 128 + 8 * c4));
#pragma unroll
            for (int u = 0; u < 4; u++) {
                float g = fsigmoid((float)z[2 * u] * ag[u] + bg[u]);
                float s = fsoftplus((float)z[2 * u + 1] * ac[u] + bc[u]);
                a[u] += g * s;
            }
        }
#pragma unroll
        for (int u = 0; u < 4; u++) {
            a[u] += __shfl_xor(a[u], 16, 64);
            a[u] += __shfl_xor(a[u], 32, 64);
        }
        if (sub == 0) {
            float dn = fmaxf((float)d, 1.f);
            float rr[4];
#pragma unroll
            for (int u = 0; u < 4; u++) {
                rr[u] = __fdividef(a[u], dn);
                p1[u] += rr[u];
                p2[u] += rr[u] * rr[u];
            }
            float4 r4;
            r4.x = rr[0]; r4.y = rr[1]; r4.z = rr[2]; r4.w = rr[3];
            *reinterpret_cast<float4*>(raw_out + (size_t)n * 64 + 4 * c4) = r4;
        }
    }
    if (sub == 0) {
#pragma unroll
        for (int u = 0; u < 4; u++) {
            atomicAdd(&sstat[4 * c4 + u], p1[u]);
            atomicAdd(&sstat[64 + 4 * c4 + u], p2[u]);
        }
    }
    __syncthreads();
    if (tid < 128) atomicAdd(&nstats[tid], sstat[tid]);
}

// ---------- node apply: BN2 + softplus (+ crystal pool on last layer) ----------
template <bool LAST>
__global__ __launch_bounds__(256) void k_node_apply(
    const float* __restrict__ raw_in, const float* __restrict__ nstats,
    const float* __restrict__ g2, const float* __restrict__ be2,
    float* __restrict__ xf, f16* __restrict__ x16, const int* __restrict__ idx3,
    float* __restrict__ crsum) {
    for (int idx = blockIdx.x * blockDim.x + threadIdx.x; idx < NN * 64;
         idx += gridDim.x * blockDim.x) {
        int n = idx >> 6, j = idx & 63;
        float m = nstats[j] * (1.f / NN);
        float var = nstats[64 + j] * (1.f / NN) - m * m;
        float rs = rsqrtf(var + EPSB);
        float a = g2[j] * rs;
        float b = be2[j] - m * a;
        float v = fsoftplus(xf[idx] + raw_in[idx] * a + b);
        if (LAST) {
            atomicAdd(&crsum[(size_t)idx3[n] * 64 + j], v);
        } else {
            xf[idx] = v;
            x16[idx] = (f16)v;
        }
    }
}

// ---------- output MLP ----------
__global__ __launch_bounds__(128) void k_out(const float* __restrict__ crsum,
                                             const float* __restrict__ cnt3,
                                             const float* __restrict__ Wc,
                                             const float* __restrict__ bcv,
                                             const float* __restrict__ Wo,
                                             const float* __restrict__ bo,
                                             float* __restrict__ out) {
    __shared__ float crym[64];
    __shared__ float red[4];
    int c = blockIdx.x, tid = threadIdx.x;
    if (tid < 64) crym[tid] = crsum[c * 64 + tid] / fmaxf(cnt3[c], 1.f);
    __syncthreads();
    float hv = bcv[tid];
#pragma unroll
    for (int k = 0; k < 64; k++) hv += crym[k] * Wc[k * 128 + tid];
    hv = fsoftplus(hv);
    float o0 = hv * Wo[tid * 2 + 0];
    float o1 = hv * Wo[tid * 2 + 1];
#pragma unroll
    for (int off = 32; off > 0; off >>= 1) {
        o0 += __shfl_down(o0, off, 64);
        o1 += __shfl_down(o1, off, 64);
    }
    int wv = tid >> 6;
    if ((tid & 63) == 0) { red[wv * 2] = o0; red[wv * 2 + 1] = o1; }
    __syncthreads();
    if (tid == 0) {
        out[c * 2 + 0] = red[0] + red[2] + bo[0];
        out[c * 2 + 1] = red[1] + red[3] + bo[1];
    }
}

// ---------- launch ----------
static inline size_t al256(size_t x) { return (x + 255) & ~(size_t)255; }

extern "C" void kernel_launch(void* const* d_in, const int* in_sizes, int n_in,
                              void* d_out, int out_size, void* d_ws, size_t ws_size,
                              hipStream_t stream) {
    const int* node_fea = (const int*)d_in[0];
    const float* edge_fea = (const float*)d_in[1];
    const int* idx1 = (const int*)d_in[2];
    const int* idx2 = (const int*)d_in[3];
    const int* idx3 = (const int*)d_in[4];
    const float* emb = (const float*)d_in[5];
    const float* Wf = (const float*)d_in[6];
    // d_in[7] = bf: cancels inside training-mode BN, unused.
    const float* g1 = (const float*)d_in[8];
    const float* be1 = (const float*)d_in[9];
    const float* g2 = (const float*)d_in[10];
    const float* be2 = (const float*)d_in[11];
    const float* Wc = (const float*)d_in[12];
    const float* bc = (const float*)d_in[13];
    const float* Wo = (const float*)d_in[14];
    const float* bo = (const float*)d_in[15];
    float* out = (float*)d_out;
    unsigned char* ws = (unsigned char*)d_ws;

    size_t off = 0;
    size_t o_xf = off;     off = al256(off + (size_t)NN * 64 * 4);
    size_t o_x16 = off;    off = al256(off + (size_t)NN * 64 * 2);
    size_t o_efp = off;    off = al256(off + (size_t)NE * EFW * 2);
    size_t o_WT = off;     off = al256(off + (size_t)128 * KPAD * 2);
    size_t o_rp1 = off;    off = al256(off + (size_t)NN * 4);
    size_t o_el1 = off;    off = al256(off + (size_t)NE * 4);
    size_t o_i1r = off;    off = al256(off + (size_t)NE * 4);
    size_t o_i2r = off;    off = al256(off + (size_t)NE * 4);
    size_t o_raw = off;    off = al256(off + (size_t)NN * 64 * 4);
    // prep-zero region (one memset):
    size_t o_deg1 = off;   off = al256(off + (size_t)NN * 4);
    size_t o_cur1 = off;   off = al256(off + (size_t)NN * 4);
    size_t o_cnt3 = off;   off = al256(off + (size_t)NC * 4);
    size_t o_csum = off;   off = al256(off + 1024 * 4);
    size_t o_coff = off;   off = al256(off + 1024 * 4);
    size_t o_crsum = off;  off = al256(off + (size_t)NC * 64 * 4);
    size_t prep_zero_end = off;
    // per-layer-zero region (tiny memset per layer):
    size_t o_estats = off; off = al256(off + 256 * 4);
    size_t o_nstats = off; off = al256(off + 128 * 4);
    size_t layer_zero_end = off;
    size_t o_z = off;      off = al256(off + (size_t)NE * 64 * 4);
    (void)ws_size;

    float* xf = (float*)(ws + o_xf);
    f16* x16 = (f16*)(ws + o_x16);
    f16* ef16p = (f16*)(ws + o_efp);
    f16* WT = (f16*)(ws + o_WT);
    int* rp1 = (int*)(ws + o_rp1);
    int* elist1 = (int*)(ws + o_el1);
    int* i1r = (int*)(ws + o_i1r);
    int* i2r = (int*)(ws + o_i2r);
    float* raw = (float*)(ws + o_raw);
    int* deg1 = (int*)(ws + o_deg1);
    int* cur1 = (int*)(ws + o_cur1);
    float* cnt3 = (float*)(ws + o_cnt3);
    int* csum = (int*)(ws + o_csum);
    int* coff = (int*)(ws + o_coff);
    float* crsum = (float*)(ws + o_crsum);
    float* estats = (float*)(ws + o_estats);
    float* nstats = (float*)(ws + o_nstats);
    f16* zph = (f16*)(ws + o_z);
    half2v* zp = (half2v*)(ws + o_z);

    hipMemsetAsync(ws + o_deg1, 0, prep_zero_end - o_deg1, stream);
    k_prep_x<<<1024, 256, 0, stream>>>(node_fea, emb, xf, x16);
    k_deg<<<2048, 256, 0, stream>>>(idx1, idx3, deg1, cnt3);
    k_scan_a<<<4, 256, 0, stream>>>(deg1, csum);
    k_scan_b<<<1, 256, 0, stream>>>(csum, coff);
    k_scan_c<<<4, 256, 0, stream>>>(deg1, coff, rp1);
    k_scatter<<<2048, 256, 0, stream>>>(idx1, idx2, rp1, cur1, elist1, i1r, i2r);
    k_prep_efg<<<8192, 256, 0, stream>>>(edge_fea, elist1, ef16p);

    for (int l = 0; l < 3; l++) {
        const float* Wf_l = Wf + (size_t)l * 169 * 128;
        hipMemsetAsync(ws + o_estats, 0, layer_zero_end - o_estats, stream);
        k_wt<<<88, 256, 0, stream>>>(Wf_l, WT);
        k_edge_a<<<2048, 256, 0, stream>>>(x16, ef16p, WT, i1r, i2r, estats, zp);
        k_nodered<<<4096, 256, 0, stream>>>(zph, rp1, deg1, estats, g1 + l * 128,
                                            be1 + l * 128, raw, nstats);
        if (l < 2) {
            k_node_apply<false><<<1024, 256, 0, stream>>>(raw, nstats, g2 + l * 64,
                                                          be2 + l * 64, xf, x16,
                                                          idx3, crsum);
        } else {
            k_node_apply<true><<<1024, 256, 0, stream>>>(raw, nstats, g2 + l * 64,
                                                         be2 + l * 64, xf, x16,
                                                         idx3, crsum);
        }
    }
    k_out<<<2000, 128, 0, stream>>>(crsum, cnt3, Wc, bc, Wo, bo, out);
}